// Round 1
// 663.840 us; speedup vs baseline: 1.2004x; 1.2004x over previous
//
#include <hip/hip_runtime.h>
#include <math.h>

// Problem constants (B=8, S=2048, D=1024, DK=DV=128, FF=4096)
#define M_TOT   16384
#define D_MODEL 1024
#define D_HEAD  128
#define SEQ     2048
#define NBATCH  8
#define D_FF    4096

typedef _Float16 f16x8 __attribute__((ext_vector_type(8)));
typedef _Float16 f16x4 __attribute__((ext_vector_type(4)));
typedef float    f32x4 __attribute__((ext_vector_type(4)));

#define ATT_SCALE 0.08838834764831845f  // 1/sqrt(128)

__device__ __forceinline__ void gload_lds16(const _Float16* g, _Float16* l) {
  __builtin_amdgcn_global_load_lds(
      (const __attribute__((address_space(1))) unsigned int*)g,
      (__attribute__((address_space(3))) unsigned int*)l, 16, 0, 0);
}
__device__ __forceinline__ unsigned short f16bits(float v) {
  union { _Float16 f; unsigned short u; } cv; cv.f = (_Float16)v; return cv.u;
}
// tanh-form GELU: 0.5x(1+tanh(0.79788456(x+0.044715x^3))); overflow-safe, ~8 VALU ops
__device__ __forceinline__ float gelu_f(float x) {
  const float t = 0.7978845608028654f * x * (1.0f + 0.044715f * x * x);
  const float e = __expf(2.0f * t);
  const float th = 1.0f - 2.0f / (e + 1.0f);
  return 0.5f * x * (1.0f + th);
}
__device__ __forceinline__ void bar_sync() {
  __asm__ volatile("" ::: "memory");
  __builtin_amdgcn_s_barrier();
  __asm__ volatile("" ::: "memory");
}
// byte offset of logical (row, 16B-slot=quad) inside a [*][32] f16 tile,
// XOR-swizzled: e = ((row&1)<<2 | quad) ^ ((row>>1)&7); involution, conflict-free
// for the frag read pattern (16 consecutive rows per quarter-wave hit all 32 banks 2x).
__device__ __forceinline__ int swzb(int row, int quad) {
  const int e = (((row & 1) << 2) | quad) ^ ((row >> 1) & 7);
  return ((row >> 1) << 7) | (e << 4);
}

// ---------------- weight convert + transpose: out[n][k] = f16(in[k][n]) ----------------
__global__ __launch_bounds__(256) void convt_kernel(const float* __restrict__ in,
                                                    _Float16* __restrict__ out,
                                                    int K, int N) {
  __shared__ float t[32][33];
  const int n0 = blockIdx.x * 32, k0 = blockIdx.y * 32;
  const int tx = threadIdx.x & 31, ty = threadIdx.x >> 5;   // 32 x 8
#pragma unroll
  for (int r = 0; r < 4; r++)
    t[ty + 8 * r][tx] = in[(size_t)(k0 + ty + 8 * r) * N + n0 + tx];
  __syncthreads();
#pragma unroll
  for (int r = 0; r < 4; r++)
    out[(size_t)(n0 + ty + 8 * r) * K + k0 + tx] = (_Float16)t[tx][ty + 8 * r];
}

// ---------------- LayerNorm: one block (256 thr) per row of 1024 ----------------
template <bool WF32>
__global__ __launch_bounds__(256) void ln_kernel(const float* __restrict__ in,
                                                 const float* __restrict__ gamma,
                                                 const float* __restrict__ beta,
                                                 float* __restrict__ of,
                                                 _Float16* __restrict__ oh) {
  __shared__ float shs[4], shq[4];
  const int row = blockIdx.x;
  const int t = threadIdx.x;
  float4 v = ((const float4*)(in + (size_t)row * D_MODEL))[t];
  float s = v.x + v.y + v.z + v.w;
  float q = v.x * v.x + v.y * v.y + v.z * v.z + v.w * v.w;
#pragma unroll
  for (int o = 32; o > 0; o >>= 1) {
    s += __shfl_down(s, o, 64);
    q += __shfl_down(q, o, 64);
  }
  const int lane = t & 63, w = t >> 6;
  if (lane == 0) { shs[w] = s; shq[w] = q; }
  __syncthreads();
  if (t == 0) {
    shs[0] = shs[0] + shs[1] + shs[2] + shs[3];
    shq[0] = shq[0] + shq[1] + shq[2] + shq[3];
  }
  __syncthreads();
  const float mu = shs[0] * (1.0f / D_MODEL);
  const float var = shq[0] * (1.0f / D_MODEL) - mu * mu;
  const float rs = rsqrtf(var + 1e-5f);
  float4 gv = ((const float4*)gamma)[t];
  float4 bv = ((const float4*)beta)[t];
  float4 o;
  o.x = (v.x - mu) * rs * gv.x + bv.x;
  o.y = (v.y - mu) * rs * gv.y + bv.y;
  o.z = (v.z - mu) * rs * gv.z + bv.z;
  o.w = (v.w - mu) * rs * gv.w + bv.w;
  if (WF32) ((float4*)(of + (size_t)row * D_MODEL))[t] = o;
  f16x4 h4 = {(_Float16)o.x, (_Float16)o.y, (_Float16)o.z, (_Float16)o.w};
  ((f16x4*)(oh + (size_t)row * D_MODEL))[t] = h4;
}

// =====================================================================================
// 256x256-tile MFMA GEMM, BK=32, 512 thr = 8 waves (2Mx4N), 4-slot LDS ring (128 KiB),
// counted-vmcnt pipeline (T3+T4), XOR-swizzled LDS (T2), setprio around MFMA (T5),
// XCD-aware block swizzle (T1).  A f16 [M][K], BT f16 [N][K].
// MODE 0: C f32 = acc + bias[col] + res ; MODE 1: C f16 = gelu(acc + bias[col])
// Requires: M%256==0, N%256==0, K%32==0, K>=128, gridDim.x%8==0.
// =====================================================================================

// stage 16 rows x 32 f16 (1 KiB) per gload; LDS dest linear, global source
// pre-permuted with the inverse (= same) swizzle so read-side swzb() sees logical data.
#define STAGE_A(JT)                                                       \
  {                                                                       \
    _Float16* ps_ = SM + (((JT) & 3) * 16384) + ldsA;                     \
    const size_t kp_ = (size_t)(JT) * 32;                                 \
    gload_lds16(Ag0 + kp_, ps_);                                          \
    gload_lds16(Ag0 + 16 * (size_t)K + kp_, ps_ + 512);                   \
  }
#define STAGE_B(JT)                                                       \
  {                                                                       \
    _Float16* ps_ = SM + (((JT) & 3) * 16384) + ldsB;                     \
    const size_t kp_ = (size_t)(JT) * 32;                                 \
    gload_lds16(Bg0 + kp_, ps_);                                          \
    gload_lds16(Bg0 + 16 * (size_t)K + kp_, ps_ + 512);                   \
  }

// One K-tile = 2 phases x 16 MFMA. Per phase: ds_read frag subtile, issue one
// half-prefetch (tile JT+3), barrier, lgkmcnt(0)+sched_barrier (rule 18), setprio'd
// MFMA cluster, barrier. vmcnt(WSTR) once per tile, before phase B's opening barrier:
// guarantees tile JT+1 landed in every wave before any wave reads it next tile.
#define KTILE(JT, WSTR, PF)                                                    \
  {                                                                            \
    _Float16* sb_ = SM + (((JT) & 3) * 16384);                                 \
    const char* Ab_ = (const char*)sb_;                                        \
    const char* Bb_ = (const char*)(sb_ + 8192);                               \
    f16x8 af[8], bfr[4];                                                       \
    _Pragma("unroll") for (int m = 0; m < 8; ++m)                              \
        af[m] = *(const f16x8*)(Ab_ + swzb(wm * 128 + m * 16 + l15, quad));    \
    bfr[0] = *(const f16x8*)(Bb_ + swzb(wn * 64 + l15, quad));                 \
    bfr[1] = *(const f16x8*)(Bb_ + swzb(wn * 64 + 16 + l15, quad));            \
    if (PF) { STAGE_A((JT) + 3); }                                             \
    bar_sync();                                                                \
    asm volatile("s_waitcnt lgkmcnt(0)" ::: "memory");                         \
    __builtin_amdgcn_sched_barrier(0);                                         \
    __builtin_amdgcn_s_setprio(1);                                             \
    _Pragma("unroll") for (int m = 0; m < 8; ++m) {                            \
      acc[m][0] = __builtin_amdgcn_mfma_f32_16x16x32_f16(af[m], bfr[0], acc[m][0], 0, 0, 0); \
      acc[m][1] = __builtin_amdgcn_mfma_f32_16x16x32_f16(af[m], bfr[1], acc[m][1], 0, 0, 0); \
    }                                                                          \
    __builtin_amdgcn_s_setprio(0);                                             \
    bar_sync();                                                                \
    bfr[2] = *(const f16x8*)(Bb_ + swzb(wn * 64 + 32 + l15, quad));            \
    bfr[3] = *(const f16x8*)(Bb_ + swzb(wn * 64 + 48 + l15, quad));            \
    if (PF) { STAGE_B((JT) + 3); }                                             \
    asm volatile("s_waitcnt " WSTR ::: "memory");                              \
    bar_sync();                                                                \
    asm volatile("s_waitcnt lgkmcnt(0)" ::: "memory");                         \
    __builtin_amdgcn_sched_barrier(0);                                         \
    __builtin_amdgcn_s_setprio(1);                                             \
    _Pragma("unroll") for (int m = 0; m < 8; ++m) {                            \
      acc[m][2] = __builtin_amdgcn_mfma_f32_16x16x32_f16(af[m], bfr[2], acc[m][2], 0, 0, 0); \
      acc[m][3] = __builtin_amdgcn_mfma_f32_16x16x32_f16(af[m], bfr[3], acc[m][3], 0, 0, 0); \
    }                                                                          \
    __builtin_amdgcn_s_setprio(0);                                             \
    bar_sync();                                                                \
  }

template <int MODE>
__global__ __launch_bounds__(512, 2) void mfma_gemm256(
    const _Float16* __restrict__ A, const _Float16* __restrict__ BT,
    const float* __restrict__ bias, const float* __restrict__ res,
    void* __restrict__ Cout, int M, int N, int K) {
  __shared__ __attribute__((aligned(16))) _Float16 SM[4 * 16384];  // 4 ring slots x (A 8192 | B 8192) f16
  const int tid = threadIdx.x;
  const int lane = tid & 63, w = tid >> 6;
  const int l15 = lane & 15, quad = lane >> 4;
  const int wm = w >> 2, wn = w & 3;

  // T1: XCD-aware swizzle (consecutive logical ids -> same XCD; gridDim.x%8==0)
  const int nwg = gridDim.x;
  const int bid = (blockIdx.x & 7) * (nwg >> 3) + (blockIdx.x >> 3);
  const int nbx = N >> 8;
  const int bx = bid % nbx, by = bid / nbx;
  const int row0 = by << 8, col0 = bx << 8;

  // per-lane pre-swizzled global source for the linear-dest global_load_lds:
  // lane L writes LDS phys slot (rp=L>>3, e=L&7); logical = sigma(phys).
  const int rp = lane >> 3;
  const int el = (lane & 7) ^ rp;
  const int lr = (rp << 1) | (el >> 2);   // logical row in 16-row group
  const int lc = (el & 3) << 3;           // logical f16 col offset
  const _Float16* Ag0 = A + (size_t)(row0 + w * 32 + lr) * K + lc;
  const _Float16* Bg0 = BT + (size_t)(col0 + w * 32 + lr) * K + lc;
  const int ldsA = w * 1024;
  const int ldsB = 8192 + w * 1024;

  const f32x4 zero = {0.f, 0.f, 0.f, 0.f};
  f32x4 acc[8][4];
#pragma unroll
  for (int m = 0; m < 8; ++m)
#pragma unroll
    for (int n = 0; n < 4; ++n) acc[m][n] = zero;

  const int NKT = K >> 5;
  // prologue: stage K-tiles 0..2 (12 loads/wave), land tile 0, keep 8 in flight
  for (int t = 0; t < 3; ++t) { STAGE_A(t); STAGE_B(t); }
  asm volatile("s_waitcnt vmcnt(8)" ::: "memory");
  bar_sync();

  int j = 0;
#pragma unroll 1
  for (; j + 3 < NKT; ++j) { KTILE(j, "vmcnt(8)", 1); }
  KTILE(j, "vmcnt(4)", 0); ++j;   // NKT-3: only tile NKT-1 may stay in flight
  KTILE(j, "vmcnt(0)", 0); ++j;   // NKT-2: drain
  KTILE(j, "vmcnt(0)", 0);        // NKT-1 (wait is free: nothing outstanding)

  // epilogue. C/D layout: col = l15, row = quad*4 + r  [verified earlier rounds]
  const int colb = col0 + wn * 64 + l15;
  if (MODE == 0) {
    float* C = (float*)Cout;
    float bv[4];
#pragma unroll
    for (int n = 0; n < 4; ++n) bv[n] = bias[colb + n * 16];
#pragma unroll
    for (int m = 0; m < 8; ++m)
#pragma unroll
      for (int r = 0; r < 4; ++r) {
        const int row = row0 + wm * 128 + m * 16 + quad * 4 + r;
        const size_t base = (size_t)row * N + colb;
        const float* rp2 = res + base;
        float* cp = C + base;
#pragma unroll
        for (int n = 0; n < 4; ++n) cp[n * 16] = acc[m][n][r] + bv[n] + rp2[n * 16];
      }
  } else {
    _Float16* C = (_Float16*)Cout;
    float bv[4];
#pragma unroll
    for (int n = 0; n < 4; ++n) bv[n] = bias[colb + n * 16];
#pragma unroll
    for (int m = 0; m < 8; ++m)
#pragma unroll
      for (int r = 0; r < 4; ++r) {
        const int row = row0 + wm * 128 + m * 16 + quad * 4 + r;
        _Float16* cp = C + (size_t)row * N + colb;
#pragma unroll
        for (int n = 0; n < 4; ++n) cp[n * 16] = (_Float16)gelu_f(acc[m][n][r] + bv[n]);
      }
  }
  (void)M;
}

// ---------------- old 128x128 MFMA GEMM (kept for fused QKV, MODE 2) ----------------
template <int MODE>
__global__ __launch_bounds__(256) void mfma_gemm(const _Float16* __restrict__ A,
                                                 const _Float16* __restrict__ BT,
                                                 const float* __restrict__ b0p,
                                                 const float* __restrict__ b1p,
                                                 const float* __restrict__ b2p,
                                                 const float* __restrict__ res,
                                                 void* __restrict__ Cout,
                                                 _Float16* __restrict__ vtout,
                                                 int M, int N, int K) {
  __shared__ _Float16 SMEM[2 * 128 * 32];   // As | Bs ; aliased as Ts in MODE2-V epilogue
  _Float16* As = SMEM;
  _Float16* Bs = SMEM + 128 * 32;
  const int tid = threadIdx.x;
  const int lane = tid & 63, w = tid >> 6;
  const int wr = w >> 1, wc = w & 1;
  const int row0 = blockIdx.y << 7, col0 = blockIdx.x << 7;
  const int l15 = lane & 15, quad = lane >> 4;
  const f32x4 zero = {0.f, 0.f, 0.f, 0.f};
  f32x4 acc[4][4];
#pragma unroll
  for (int i = 0; i < 4; i++)
#pragma unroll
    for (int j = 0; j < 4; j++) acc[i][j] = zero;

  const int srow = lane >> 2;          // 0..15
  const int scol = (lane & 3) << 3;    // 0,8,16,24
  const _Float16* Ag = A + (size_t)(row0 + w * 32 + srow) * K + scol;
  const _Float16* Bg = BT + (size_t)(col0 + w * 32 + srow) * K + scol;

  for (int k0 = 0; k0 < K; k0 += 32) {
#pragma unroll
    for (int p = 0; p < 2; p++) {
      gload_lds16(Ag + (size_t)(p * 16) * K + k0, &As[(w * 32 + p * 16) * 32]);
      gload_lds16(Bg + (size_t)(p * 16) * K + k0, &Bs[(w * 32 + p * 16) * 32]);
    }
    __syncthreads();
    f16x8 af[4], bfr[4];
#pragma unroll
    for (int i = 0; i < 4; i++) {
      af[i]  = *(const f16x8*)&As[(wr * 64 + i * 16 + l15) * 32 + quad * 8];
      bfr[i] = *(const f16x8*)&Bs[(wc * 64 + i * 16 + l15) * 32 + quad * 8];
    }
#pragma unroll
    for (int i = 0; i < 4; i++)
#pragma unroll
      for (int j = 0; j < 4; j++)
        acc[i][j] = __builtin_amdgcn_mfma_f32_16x16x32_f16(af[i], bfr[j], acc[i][j], 0, 0, 0);
    __syncthreads();
  }

  // Epilogue. C/D layout: col = l15, row = quad*4 + r
  if (MODE == 0) {
    float* C = (float*)Cout;
    float bv4[4];
#pragma unroll
    for (int j = 0; j < 4; j++) bv4[j] = b0p[col0 + wc * 64 + j * 16 + l15];
#pragma unroll
    for (int i = 0; i < 4; i++)
#pragma unroll
      for (int r = 0; r < 4; r++) {
        const int row = row0 + wr * 64 + i * 16 + quad * 4 + r;
        const size_t base = (size_t)row * N + col0 + wc * 64 + l15;
        const float* rp = res + base;
        float* cp = C + base;
#pragma unroll
        for (int j = 0; j < 4; j++)
          cp[j * 16] = acc[i][j][r] + bv4[j] + rp[j * 16];
      }
  } else if (MODE == 1) {
    _Float16* C = (_Float16*)Cout;
    float bv4[4];
#pragma unroll
    for (int j = 0; j < 4; j++) bv4[j] = b0p[col0 + wc * 64 + j * 16 + l15];
#pragma unroll
    for (int i = 0; i < 4; i++)
#pragma unroll
      for (int r = 0; r < 4; r++) {
        const int row = row0 + wr * 64 + i * 16 + quad * 4 + r;
        _Float16* cp = C + (size_t)row * N + col0 + wc * 64 + l15;
#pragma unroll
        for (int j = 0; j < 4; j++)
          cp[j * 16] = (_Float16)gelu_f(acc[i][j][r] + bv4[j]);
      }
  } else {
    _Float16* qkout = (_Float16*)Cout;
    const int bx = blockIdx.x;
    if (bx < 2) {
      // q (scaled) or k -> qk[M][256]
      const float* bp = (bx == 0) ? b0p : b1p;
      const float sc = (bx == 0) ? ATT_SCALE : 1.0f;
      const int cofs = bx * 128 + wc * 64 + l15;
      float bv4[4];
#pragma unroll
      for (int j = 0; j < 4; j++) bv4[j] = bp[wc * 64 + j * 16 + l15];
#pragma unroll
      for (int i = 0; i < 4; i++)
#pragma unroll
        for (int r = 0; r < 4; r++) {
          const int row = row0 + wr * 64 + i * 16 + quad * 4 + r;
          _Float16* cp = qkout + (size_t)row * 256 + cofs;
#pragma unroll
          for (int j = 0; j < 4; j++)
            cp[j * 16] = (_Float16)((acc[i][j][r] + bv4[j]) * sc);
        }
    } else {
      // v -> vt[B][128][S], via LDS transpose (Ts[vd][40] f16, aliases SMEM)
      _Float16* Ts = SMEM;
      float bv4[4];
#pragma unroll
      for (int j = 0; j < 4; j++) bv4[j] = b2p[wc * 64 + j * 16 + l15];
      const int bb = row0 >> 11, s0 = row0 & 2047;
#pragma unroll
      for (int c = 0; c < 4; c++) {        // s-chunk [c*32, c*32+32)
        __syncthreads();
        if (wr == (c >> 1)) {
#pragma unroll
          for (int ii = 0; ii < 2; ii++) {
            const int i = (c & 1) * 2 + ii;
#pragma unroll
            for (int j = 0; j < 4; j++) {
              const int vd = wc * 64 + j * 16 + l15;
              const int slocal = ii * 16 + quad * 4;
              ushort4 h;
              h.x = f16bits(acc[i][j][0] + bv4[j]);
              h.y = f16bits(acc[i][j][1] + bv4[j]);
              h.z = f16bits(acc[i][j][2] + bv4[j]);
              h.w = f16bits(acc[i][j][3] + bv4[j]);
              *(ushort4*)&Ts[vd * 40 + slocal] = h;
            }
          }
        }
        __syncthreads();
#pragma unroll
        for (int p = 0; p < 2; p++) {
          const int idx = tid + p * 256;       // 0..511
          const int vd = idx >> 2, s8 = (idx & 3) * 8;
          uint4 d = *(const uint4*)&Ts[vd * 40 + s8];
          *(uint4*)&vtout[((size_t)bb * 128 + vd) * SEQ + s0 + c * 32 + s8] = d;
        }
      }
    }
  }
}

// ---------------- MFMA flash attention ----------------
// Grid (SEQ/64, B), 256 thr = 4 waves, 16 queries/wave. 64-key tiles.
// qk: [B*S][256] f16 (q pre-scaled, k). vt: [B][128][S] f16. H: [B*S][128] f16.
__global__ __launch_bounds__(256) void flash_attn_mfma(const _Float16* __restrict__ qk,
                                                       const _Float16* __restrict__ vt,
                                                       _Float16* __restrict__ H) {
  __shared__ _Float16 Ks[2][64][136];   // keys x d, pad 8
  __shared__ _Float16 Vs[128][72];      // d x keys, pad 8
  __shared__ _Float16 Ps[4][16][72];    // per-wave P: q x keys, pad 8
  const int b = blockIdx.y, q0 = blockIdx.x * 64;
  const int tid = threadIdx.x;
  const int lane = tid & 63, w = tid >> 6;
  const int l15 = lane & 15, quad = lane >> 4;

  // Q fragments (A-layout), q pre-scaled by 1/sqrt(dk)
  f16x8 qf[4];
  {
    const _Float16* qrow = qk + ((size_t)(b * SEQ + q0 + w * 16 + l15)) * 256 + quad * 8;
#pragma unroll
    for (int ks = 0; ks < 4; ks++) qf[ks] = *(const f16x8*)(qrow + ks * 32);
  }
  const f32x4 zero = {0.f, 0.f, 0.f, 0.f};
  f32x4 O[8];
#pragma unroll
  for (int i = 0; i < 8; i++) O[i] = zero;
  float m_r[4] = {-1e30f, -1e30f, -1e30f, -1e30f};
  float l_r[4] = {0.f, 0.f, 0.f, 0.f};

  const _Float16* kg0 = qk + (size_t)(b * SEQ) * 256 + 128 + (size_t)(tid >> 4) * 256 + (tid & 15) * 8;
  const _Float16* vg0 = vt + (size_t)b * 128 * SEQ + (size_t)((tid >> 3)) * SEQ + (tid & 7) * 8;
  uint4 kp[4], vp[4];

#define LOAD_TILE(kt)                                                            \
  {                                                                              \
    const _Float16* kg = kg0 + (size_t)(kt) * 64 * 256;                          \
    const _Float16* vg = vg0 + (size_t)(kt) * 64;                                \
    _Pragma("unroll") for (int p = 0; p < 4; p++) {                              \
      kp[p] = *(const uint4*)(kg + (size_t)p * 16 * 256);                        \
      vp[p] = *(const uint4*)(vg + (size_t)p * 32 * SEQ);                        \
    }                                                                            \
  }
#define STORE_K(buf)                                                             \
  _Pragma("unroll") for (int p = 0; p < 4; p++)                                  \
      *(uint4*)&Ks[buf][(tid >> 4) + 16 * p][(tid & 15) * 8] = kp[p];
#define STORE_V()                                                                \
  _Pragma("unroll") for (int p = 0; p < 4; p++)                                  \
      *(uint4*)&Vs[(tid >> 3) + 32 * p][(tid & 7) * 8] = vp[p];

  LOAD_TILE(0);
  STORE_K(0);
  STORE_V();
  __syncthreads();

  const int NT = SEQ / 64;
  for (int kt = 0; kt < NT; kt++) {
    const int cur = kt & 1;
    if (kt + 1 < NT) LOAD_TILE(kt + 1);

    // S = Q K^T  (4 key-tiles of 16)
    f32x4 s4[4];
#pragma unroll
    for (int nt = 0; nt < 4; nt++) {
      s4[nt] = zero;
#pragma unroll
      for (int ks = 0; ks < 4; ks++) {
        f16x8 kf = *(const f16x8*)&Ks[cur][nt * 16 + l15][ks * 32 + quad * 8];
        s4[nt] = __builtin_amdgcn_mfma_f32_16x16x32_f16(qf[ks], kf, s4[nt], 0, 0, 0);
      }
    }
    // online softmax; row = quad*4 + r, spread over 16 l15 lanes
    float rmax[4], alpha[4], rsum[4];
#pragma unroll
    for (int r = 0; r < 4; r++)
      rmax[r] = fmaxf(fmaxf(s4[0][r], s4[1][r]), fmaxf(s4[2][r], s4[3][r]));
#pragma unroll
    for (int o = 1; o < 16; o <<= 1)
#pragma unroll
      for (int r = 0; r < 4; r++) rmax[r] = fmaxf(rmax[r], __shfl_xor(rmax[r], o, 64));
#pragma unroll
    for (int r = 0; r < 4; r++) {
      const float nm = fmaxf(m_r[r], rmax[r]);
      alpha[r] = __expf(m_r[r] - nm);
      m_r[r] = nm;
#pragma unroll
      for (int nt = 0; nt < 4; nt++) s4[nt][r] = __expf(s4[nt][r] - nm);
      rsum[r] = s4[0][r] + s4[1][r] + s4[2][r] + s4[3][r];
    }
#pragma unroll
    for (int o = 1; o < 16; o <<= 1)
#pragma unroll
      for (int r = 0; r < 4; r++) rsum[r] += __shfl_xor(rsum[r], o, 64);
#pragma unroll
    for (int r = 0; r < 4; r++) {
      l_r[r] = l_r[r] * alpha[r] + rsum[r];
#pragma unroll
      for (int i = 0; i < 8; i++) O[i][r] *= alpha[r];
    }
    // P -> LDS (C-layout write), read back in A-layout (same wave, in-order DS)
#pragma unroll
    for (int nt = 0; nt < 4; nt++)
#pragma unroll
      for (int r = 0; r < 4; r++)
        Ps[w][quad * 4 + r][nt * 16 + l15] = (_Float16)s4[nt][r];
    f16x8 pa[2];
#pragma unroll
    for (int ks = 0; ks < 2; ks++)
      pa[ks] = *(const f16x8*)&Ps[w][l15][ks * 32 + quad * 8];
    // O += P @ V  (8 vdim-tiles of 16)
#pragma unroll
    for (int ks = 0; ks < 2; ks++)
#pragma unroll
      for (int vt8 = 0; vt8 < 8; vt8++) {
        f16x8 vf = *(const f16x8*)&Vs[vt8 * 16 + l15][ks * 32 + quad * 8];
        O[vt8] = __builtin_amdgcn_mfma_f32_16x16x32_f16(pa[ks], vf, O[vt8], 0, 0, 0);
      }

    if (kt + 1 < NT) {
      STORE_K(cur ^ 1);        // other K buffer: safe without barrier
      __syncthreads();         // all waves done reading Vs for this tile
      STORE_V();
      __syncthreads();         // next tile K+V visible
    }
  }
  // epilogue: H[q][vd] = O / l
#pragma unroll
  for (int r = 0; r < 4; r++) {
    const float inv = 1.0f / l_r[r];
    _Float16* hp = H + (size_t)(b * SEQ + q0 + w * 16 + quad * 4 + r) * D_HEAD;
#pragma unroll
    for (int vt8 = 0; vt8 < 8; vt8++)
      hp[vt8 * 16 + l15] = (_Float16)(O[vt8][r] * inv);
  }
}

// ---------------- launch ----------------
extern "C" void kernel_launch(void* const* d_in, const int* in_sizes, int n_in,
                              void* d_out, int out_size, void* d_ws, size_t ws_size,
                              hipStream_t stream) {
  const float* x     = (const float*)d_in[0];
  const float* ln1_g = (const float*)d_in[1];
  const float* ln1_b = (const float*)d_in[2];
  const float* Wq    = (const float*)d_in[3];
  const float* bq    = (const float*)d_in[4];
  const float* Wk    = (const float*)d_in[5];
  const float* bk    = (const float*)d_in[6];
  const float* Wv    = (const float*)d_in[7];
  const float* bv    = (const float*)d_in[8];
  const float* Wo    = (const float*)d_in[9];
  const float* bo    = (const float*)d_in[10];
  const float* ln2_g = (const float*)d_in[11];
  const float* ln2_b = (const float*)d_in[12];
  const float* W1    = (const float*)d_in[13];
  const float* b1    = (const float*)d_in[14];
  const float* W2    = (const float*)d_in[15];
  const float* b2    = (const float*)d_in[16];
  float* out = (float*)d_out;

  // Workspace (<=180 MiB), lifetime-overlapped:
  //  [0,8M) W1T | [8,16M) W2T | [16,16.75M) WqkvT | [16.75,17M) WoT
  //  [20,84M) xn_f32 (K1..K4) | [84,116M) xn_f16 (K1..K2)
  //  [116,124M) qk (K2..K3) | [124,128M) vt (K2..K3) | [128,132M) Hb (K3..K4)
  //  [20,148M) act f16 (K6..K7, reuses dead buffers) | [148,180M) h16 (K5..K6)
  char* ws = (char*)d_ws;
  const size_t MB = 1024 * 1024;
  _Float16* W1T   = (_Float16*)(ws);
  _Float16* W2T   = (_Float16*)(ws + 8 * MB);
  _Float16* WqkvT = (_Float16*)(ws + 16 * MB);
  _Float16* WoT   = (_Float16*)(ws + 16 * MB + 768 * 1024);
  float*    xn_f32 = (float*)(ws + 20 * MB);
  _Float16* xn_f16 = (_Float16*)(ws + 84 * MB);
  _Float16* qkb  = (_Float16*)(ws + 116 * MB);
  _Float16* vtb  = (_Float16*)(ws + 124 * MB);
  _Float16* Hb   = (_Float16*)(ws + 128 * MB);
  _Float16* act  = (_Float16*)(ws + 20 * MB);
  _Float16* h16  = (_Float16*)(ws + 148 * MB);

  // K0: weight convert+transpose (Wq/Wk/Wv into one contiguous [384][1024])
  convt_kernel<<<dim3(D_FF / 32, D_MODEL / 32), 256, 0, stream>>>(W1, W1T, D_MODEL, D_FF);
  convt_kernel<<<dim3(D_MODEL / 32, D_FF / 32), 256, 0, stream>>>(W2, W2T, D_FF, D_MODEL);
  convt_kernel<<<dim3(D_HEAD / 32, D_MODEL / 32), 256, 0, stream>>>(Wq, WqkvT, D_MODEL, D_HEAD);
  convt_kernel<<<dim3(D_HEAD / 32, D_MODEL / 32), 256, 0, stream>>>(Wk, WqkvT + 128 * 1024, D_MODEL, D_HEAD);
  convt_kernel<<<dim3(D_HEAD / 32, D_MODEL / 32), 256, 0, stream>>>(Wv, WqkvT + 256 * 1024, D_MODEL, D_HEAD);
  convt_kernel<<<dim3(D_MODEL / 32, D_HEAD / 32), 256, 0, stream>>>(Wo, WoT, D_HEAD, D_MODEL);
  // K1: LN1
  ln_kernel<true><<<dim3(M_TOT), 256, 0, stream>>>(x, ln1_g, ln1_b, xn_f32, xn_f16);
  // K2: fused QKV projection -> qk[M][256] (q scaled) + vt[B][128][S]
  mfma_gemm<2><<<dim3(3, M_TOT / 128), 256, 0, stream>>>(
      xn_f16, WqkvT, bq, bk, bv, nullptr, qkb, vtb, M_TOT, 384, D_MODEL);
  // K3: flash attention -> Hb f16
  flash_attn_mfma<<<dim3(SEQ / 64, NBATCH), 256, 0, stream>>>(qkb, vtb, Hb);
  // K4: y = xn + H @ Wo + bo -> out f32  (pipelined 256^2 GEMM, NKT=4)
  mfma_gemm256<0><<<dim3((D_MODEL / 256) * (M_TOT / 256)), 512, 0, stream>>>(
      Hb, WoT, bo, xn_f32, out, M_TOT, D_MODEL, D_HEAD);
  // K5: LN2 -> h16
  ln_kernel<false><<<dim3(M_TOT), 256, 0, stream>>>(out, ln2_g, ln2_b, nullptr, h16);
  // K6: act = gelu(h @ W1 + b1) f16
  mfma_gemm256<1><<<dim3((D_FF / 256) * (M_TOT / 256)), 512, 0, stream>>>(
      h16, W1T, b1, nullptr, act, M_TOT, D_FF, D_MODEL);
  // K7: out = y + act @ W2 + b2
  mfma_gemm256<0><<<dim3((D_MODEL / 256) * (M_TOT / 256)), 512, 0, stream>>>(
      act, W2T, b2, out, out, M_TOT, D_MODEL, D_FF);

  (void)in_sizes; (void)n_in; (void)out_size; (void)ws_size;
}

// Round 4
// 646.531 us; speedup vs baseline: 1.2325x; 1.0268x over previous
//
#include <hip/hip_runtime.h>
#include <math.h>

// Problem constants (B=8, S=2048, D=1024, DK=DV=128, FF=4096)
#define M_TOT   16384
#define D_MODEL 1024
#define D_HEAD  128
#define SEQ     2048
#define NBATCH  8
#define D_FF    4096

typedef _Float16 f16x8 __attribute__((ext_vector_type(8)));
typedef _Float16 f16x4 __attribute__((ext_vector_type(4)));
typedef float    f32x4 __attribute__((ext_vector_type(4)));

#define ATT_SCALE 0.08838834764831845f  // 1/sqrt(128)

__device__ __forceinline__ void gload_lds16(const _Float16* g, _Float16* l) {
  __builtin_amdgcn_global_load_lds(
      (const __attribute__((address_space(1))) unsigned int*)g,
      (__attribute__((address_space(3))) unsigned int*)l, 16, 0, 0);
}
__device__ __forceinline__ unsigned short f16bits(float v) {
  union { _Float16 f; unsigned short u; } cv; cv.f = (_Float16)v; return cv.u;
}
// tanh-form GELU: 0.5x(1+tanh(0.79788456(x+0.044715x^3))); overflow-safe, ~8 VALU ops
__device__ __forceinline__ float gelu_f(float x) {
  const float t = 0.7978845608028654f * x * (1.0f + 0.044715f * x * x);
  const float e = __expf(2.0f * t);
  const float th = 1.0f - 2.0f / (e + 1.0f);
  return 0.5f * x * (1.0f + th);
}
__device__ __forceinline__ void bar_sync() {
  __asm__ volatile("" ::: "memory");
  __builtin_amdgcn_s_barrier();
  __asm__ volatile("" ::: "memory");
}
// byte offset of logical (row, 16B-slot=quad) inside a [*][32] f16 tile,
// XOR-swizzled: e = ((row&1)<<2 | quad) ^ ((row>>1)&7); involution, conflict-free.
__device__ __forceinline__ int swzb(int row, int quad) {
  const int e = (((row & 1) << 2) | quad) ^ ((row >> 1) & 7);
  return ((row >> 1) << 7) | (e << 4);
}
// raw ds_read_b128 with immediate offset (exact instruction control for the
// software-pipelined fragment loads; rule 18 handled by sched_barrier at use site)
__device__ __forceinline__ void ds_read128o(f16x8& d, unsigned addr, int imm) {
  asm volatile("ds_read_b128 %0, %1 offset:%2" : "=v"(d) : "v"(addr), "i"(imm));
}

// ---------------- weight convert + transpose: out[n][k] = f16(in[k][n]) ----------------
__global__ __launch_bounds__(256) void convt_kernel(const float* __restrict__ in,
                                                    _Float16* __restrict__ out,
                                                    int K, int N) {
  __shared__ float t[32][33];
  const int n0 = blockIdx.x * 32, k0 = blockIdx.y * 32;
  const int tx = threadIdx.x & 31, ty = threadIdx.x >> 5;   // 32 x 8
#pragma unroll
  for (int r = 0; r < 4; r++)
    t[ty + 8 * r][tx] = in[(size_t)(k0 + ty + 8 * r) * N + n0 + tx];
  __syncthreads();
#pragma unroll
  for (int r = 0; r < 4; r++)
    out[(size_t)(n0 + ty + 8 * r) * K + k0 + tx] = (_Float16)t[tx][ty + 8 * r];
}

// ---------------- LayerNorm: one block (256 thr) per row of 1024 ----------------
template <bool WF32>
__global__ __launch_bounds__(256) void ln_kernel(const float* __restrict__ in,
                                                 const float* __restrict__ gamma,
                                                 const float* __restrict__ beta,
                                                 float* __restrict__ of,
                                                 _Float16* __restrict__ oh) {
  __shared__ float shs[4], shq[4];
  const int row = blockIdx.x;
  const int t = threadIdx.x;
  float4 v = ((const float4*)(in + (size_t)row * D_MODEL))[t];
  float s = v.x + v.y + v.z + v.w;
  float q = v.x * v.x + v.y * v.y + v.z * v.z + v.w * v.w;
#pragma unroll
  for (int o = 32; o > 0; o >>= 1) {
    s += __shfl_down(s, o, 64);
    q += __shfl_down(q, o, 64);
  }
  const int lane = t & 63, w = t >> 6;
  if (lane == 0) { shs[w] = s; shq[w] = q; }
  __syncthreads();
  if (t == 0) {
    shs[0] = shs[0] + shs[1] + shs[2] + shs[3];
    shq[0] = shq[0] + shq[1] + shq[2] + shq[3];
  }
  __syncthreads();
  const float mu = shs[0] * (1.0f / D_MODEL);
  const float var = shq[0] * (1.0f / D_MODEL) - mu * mu;
  const float rs = rsqrtf(var + 1e-5f);
  float4 gv = ((const float4*)gamma)[t];
  float4 bv = ((const float4*)beta)[t];
  float4 o;
  o.x = (v.x - mu) * rs * gv.x + bv.x;
  o.y = (v.y - mu) * rs * gv.y + bv.y;
  o.z = (v.z - mu) * rs * gv.z + bv.z;
  o.w = (v.w - mu) * rs * gv.w + bv.w;
  if (WF32) ((float4*)(of + (size_t)row * D_MODEL))[t] = o;
  f16x4 h4 = {(_Float16)o.x, (_Float16)o.y, (_Float16)o.z, (_Float16)o.w};
  ((f16x4*)(oh + (size_t)row * D_MODEL))[t] = h4;
}

// =====================================================================================
// 256x256-tile MFMA GEMM, BK=32, 512 thr = 8 waves (2Mx4N), 4-slot LDS ring (128 KiB),
// counted-vmcnt global pipeline (T3+T4) + one-tile-ahead ds_read software pipeline
// (LDS unit runs concurrently with the MFMA cluster; only lgkmcnt(0) at iter top),
// XOR-swizzled LDS (T2), setprio around MFMA (T5), XCD-aware block swizzle (T1).
// A f16 [M][K], BT f16 [N][K].
// MODE 0: C f32 = acc + bias[col] + res ; MODE 1: C f16 = gelu(acc + bias[col])
// Requires: M%256==0, N%256==0, K%128==0 (NKT even, >=4), gridDim.x%8==0.
// =====================================================================================

struct Frag { f16x8 a[8]; f16x8 b[4]; };

// 12 exact ds_read_b128: A frags from bA (+m*1024), B frags from bB (+n*1024).
__device__ __forceinline__ void rd_frags(Frag& f, unsigned bA, unsigned bB) {
#pragma unroll
  for (int m = 0; m < 8; ++m) ds_read128o(f.a[m], bA, m * 1024);
#pragma unroll
  for (int n = 0; n < 4; ++n) ds_read128o(f.b[n], bB, n * 1024);
}
__device__ __forceinline__ void mfma32(f32x4 acc[8][4], const Frag& f) {
#pragma unroll
  for (int m = 0; m < 8; ++m)
#pragma unroll
    for (int n = 0; n < 4; ++n)
      acc[m][n] = __builtin_amdgcn_mfma_f32_16x16x32_f16(f.a[m], f.b[n], acc[m][n], 0, 0, 0);
}

// stage 16 rows x 32 f16 (1 KiB) per gload; LDS dest linear, global source
// pre-permuted with the inverse (= same) swizzle so read-side swizzle sees logical data.
#define STAGE_A(JT)                                                       \
  {                                                                       \
    _Float16* ps_ = SM + (((JT) & 3) * 16384) + ldsA;                     \
    const size_t kp_ = (size_t)(JT) * 32;                                 \
    gload_lds16(Ag0 + kp_, ps_);                                          \
    gload_lds16(Ag0 + 16 * (size_t)K + kp_, ps_ + 512);                   \
  }
#define STAGE_B(JT)                                                       \
  {                                                                       \
    _Float16* ps_ = SM + (((JT) & 3) * 16384) + ldsB;                     \
    const size_t kp_ = (size_t)(JT) * 32;                                 \
    gload_lds16(Bg0 + kp_, ps_);                                          \
    gload_lds16(Bg0 + 16 * (size_t)K + kp_, ps_ + 512);                   \
  }

// One pipeline iteration. CUR = frags for tile JT (loaded last iter);
// NXT receives frags for tile JT+1 (consumed next iter).
// RD: issue next-frag reads; PF: stage tile JT+3; WVM: -1 none / 4 / 0 vmcnt+barrier.
#define KITER(CUR, NXT, JT, RD, PF, WVM)                                       \
  {                                                                            \
    asm volatile("s_waitcnt lgkmcnt(0)" ::: "memory");                         \
    __builtin_amdgcn_sched_barrier(0);                                         \
    bar_sync();                                                                \
    if (RD) {                                                                  \
      const unsigned sb_ = ((unsigned)(((JT) + 1) & 3)) << 15;                 \
      rd_frags(NXT, fbaseA + sb_, fbaseB + sb_);                               \
    }                                                                          \
    if (PF) { STAGE_A((JT) + 3); STAGE_B((JT) + 3); }                          \
    __builtin_amdgcn_sched_barrier(0);                                         \
    __builtin_amdgcn_s_setprio(1);                                             \
    mfma32(acc, CUR);                                                          \
    __builtin_amdgcn_s_setprio(0);                                             \
    if ((WVM) == 4) { asm volatile("s_waitcnt vmcnt(4)" ::: "memory"); bar_sync(); } \
    if ((WVM) == 0) { asm volatile("s_waitcnt vmcnt(0)" ::: "memory"); bar_sync(); } \
  }

template <int MODE>
__global__ __launch_bounds__(512, 2) void mfma_gemm256(
    const _Float16* __restrict__ A, const _Float16* __restrict__ BT,
    const float* __restrict__ bias, const float* __restrict__ res,
    void* __restrict__ Cout, int M, int N, int K) {
  __shared__ __attribute__((aligned(16))) _Float16 SM[4 * 16384];  // 4 ring slots x (A 8192 | B 8192) f16
  const int tid = threadIdx.x;
  const int lane = tid & 63, w = tid >> 6;
  const int l15 = lane & 15, quad = lane >> 4;
  const int wm = w >> 2, wn = w & 3;

  // T1: XCD-aware swizzle (consecutive logical ids -> same XCD; gridDim.x%8==0)
  const int nwg = gridDim.x;
  const int bid = (blockIdx.x & 7) * (nwg >> 3) + (blockIdx.x >> 3);
  const int nbx = N >> 8;
  const int bx = bid % nbx, by = bid / nbx;
  const int row0 = by << 8, col0 = bx << 8;

  // per-lane pre-swizzled global source for the linear-dest global_load_lds:
  // lane L writes LDS phys slot (rp=L>>3, e=L&7); logical = sigma(phys).
  const int rp = lane >> 3;
  const int el = (lane & 7) ^ rp;
  const int lr = (rp << 1) | (el >> 2);   // logical row in 16-row group
  const int lc = (el & 3) << 3;           // logical f16 col offset
  const _Float16* Ag0 = A + (size_t)(row0 + w * 32 + lr) * K + lc;
  const _Float16* Bg0 = BT + (size_t)(col0 + w * 32 + lr) * K + lc;
  const int ldsA = w * 1024;
  const int ldsB = 8192 + w * 1024;

  // fragment-read base addresses (byte LDS offsets). The XOR term of swzb is
  // independent of the m/n sub-tile index (16-row steps are 0 mod 8 in row-pairs),
  // so per-frag deltas are pure +1024*m immediates folded into ds_read offsets.
  // A row block wm*128 rows -> wm*8192 bytes; B row block wn*64 rows -> wn*4096 bytes.
  const unsigned lds0 =
      (unsigned)(size_t)(__attribute__((address_space(3))) _Float16*)&SM[0];
  const unsigned esw = (unsigned)((((l15 & 1) << 2) | quad) ^ ((l15 >> 1) & 7));
  const unsigned rl128 = (unsigned)(l15 >> 1) << 7;
  const unsigned fbaseA = lds0 + (unsigned)(wm * 8192) + rl128 + (esw << 4);
  const unsigned fbaseB = lds0 + 16384u + (unsigned)(wn * 4096) + rl128 + (esw << 4);

  const f32x4 zero = {0.f, 0.f, 0.f, 0.f};
  f32x4 acc[8][4];
#pragma unroll
  for (int m = 0; m < 8; ++m)
#pragma unroll
    for (int n = 0; n < 4; ++n) acc[m][n] = zero;

  const int NKT = K >> 5;   // even, >= 4
  Frag fA, fB;

  // prologue: stage K-tiles 0..2; land 0,1; read tile 0 frags into fA
  for (int t = 0; t < 3; ++t) { STAGE_A(t); STAGE_B(t); }
  asm volatile("s_waitcnt vmcnt(4)" ::: "memory");
  bar_sync();
  rd_frags(fA, fbaseA, fbaseB);

  int j = 0;
#pragma unroll 1
  for (; j + 5 < NKT; j += 2) {
    KITER(fA, fB, j,     1, 1, 4);
    KITER(fB, fA, j + 1, 1, 1, 4);
  }
  // tail: j = NKT-4 .. NKT-1 (NKT even => current set is fA here)
  KITER(fA, fB, NKT - 4, 1, 1, 4);
  KITER(fB, fA, NKT - 3, 1, 0, 0);
  KITER(fA, fB, NKT - 2, 1, 0, -1);
  KITER(fB, fA, NKT - 1, 0, 0, -1);

  // epilogue. C/D layout: col = l15, row = quad*4 + r  [verified earlier rounds]
  const int colb = col0 + wn * 64 + l15;
  if (MODE == 0) {
    float* C = (float*)Cout;
    float bv[4];
#pragma unroll
    for (int n = 0; n < 4; ++n) bv[n] = bias[colb + n * 16];
#pragma unroll
    for (int m = 0; m < 8; ++m)
#pragma unroll
      for (int r = 0; r < 4; ++r) {
        const int row = row0 + wm * 128 + m * 16 + quad * 4 + r;
        const size_t base = (size_t)row * N + colb;
        const float* rp2 = res + base;
        float* cp = C + base;
#pragma unroll
        for (int n = 0; n < 4; ++n) cp[n * 16] = acc[m][n][r] + bv[n] + rp2[n * 16];
      }
  } else {
    _Float16* C = (_Float16*)Cout;
    float bv[4];
#pragma unroll
    for (int n = 0; n < 4; ++n) bv[n] = bias[colb + n * 16];
#pragma unroll
    for (int m = 0; m < 8; ++m)
#pragma unroll
      for (int r = 0; r < 4; ++r) {
        const int row = row0 + wm * 128 + m * 16 + quad * 4 + r;
        _Float16* cp = C + (size_t)row * N + colb;
#pragma unroll
        for (int n = 0; n < 4; ++n) cp[n * 16] = (_Float16)gelu_f(acc[m][n][r] + bv[n]);
      }
  }
  (void)M;
}

// ---------------- old 128x128 MFMA GEMM (kept for fused QKV, MODE 2) ----------------
template <int MODE>
__global__ __launch_bounds__(256) void mfma_gemm(const _Float16* __restrict__ A,
                                                 const _Float16* __restrict__ BT,
                                                 const float* __restrict__ b0p,
                                                 const float* __restrict__ b1p,
                                                 const float* __restrict__ b2p,
                                                 const float* __restrict__ res,
                                                 void* __restrict__ Cout,
                                                 _Float16* __restrict__ vtout,
                                                 int M, int N, int K) {
  __shared__ _Float16 SMEM[2 * 128 * 32];   // As | Bs ; aliased as Ts in MODE2-V epilogue
  _Float16* As = SMEM;
  _Float16* Bs = SMEM + 128 * 32;
  const int tid = threadIdx.x;
  const int lane = tid & 63, w = tid >> 6;
  const int wr = w >> 1, wc = w & 1;
  const int row0 = blockIdx.y << 7, col0 = blockIdx.x << 7;
  const int l15 = lane & 15, quad = lane >> 4;
  const f32x4 zero = {0.f, 0.f, 0.f, 0.f};
  f32x4 acc[4][4];
#pragma unroll
  for (int i = 0; i < 4; i++)
#pragma unroll
    for (int j = 0; j < 4; j++) acc[i][j] = zero;

  const int srow = lane >> 2;          // 0..15
  const int scol = (lane & 3) << 3;    // 0,8,16,24
  const _Float16* Ag = A + (size_t)(row0 + w * 32 + srow) * K + scol;
  const _Float16* Bg = BT + (size_t)(col0 + w * 32 + srow) * K + scol;

  for (int k0 = 0; k0 < K; k0 += 32) {
#pragma unroll
    for (int p = 0; p < 2; p++) {
      gload_lds16(Ag + (size_t)(p * 16) * K + k0, &As[(w * 32 + p * 16) * 32]);
      gload_lds16(Bg + (size_t)(p * 16) * K + k0, &Bs[(w * 32 + p * 16) * 32]);
    }
    __syncthreads();
    f16x8 af[4], bfr[4];
#pragma unroll
    for (int i = 0; i < 4; i++) {
      af[i]  = *(const f16x8*)&As[(wr * 64 + i * 16 + l15) * 32 + quad * 8];
      bfr[i] = *(const f16x8*)&Bs[(wc * 64 + i * 16 + l15) * 32 + quad * 8];
    }
#pragma unroll
    for (int i = 0; i < 4; i++)
#pragma unroll
      for (int j = 0; j < 4; j++)
        acc[i][j] = __builtin_amdgcn_mfma_f32_16x16x32_f16(af[i], bfr[j], acc[i][j], 0, 0, 0);
    __syncthreads();
  }

  // Epilogue. C/D layout: col = l15, row = quad*4 + r
  if (MODE == 0) {
    float* C = (float*)Cout;
    float bv4[4];
#pragma unroll
    for (int j = 0; j < 4; j++) bv4[j] = b0p[col0 + wc * 64 + j * 16 + l15];
#pragma unroll
    for (int i = 0; i < 4; i++)
#pragma unroll
      for (int r = 0; r < 4; r++) {
        const int row = row0 + wr * 64 + i * 16 + quad * 4 + r;
        const size_t base = (size_t)row * N + col0 + wc * 64 + l15;
        const float* rp = res + base;
        float* cp = C + base;
#pragma unroll
        for (int j = 0; j < 4; j++)
          cp[j * 16] = acc[i][j][r] + bv4[j] + rp[j * 16];
      }
  } else if (MODE == 1) {
    _Float16* C = (_Float16*)Cout;
    float bv4[4];
#pragma unroll
    for (int j = 0; j < 4; j++) bv4[j] = b0p[col0 + wc * 64 + j * 16 + l15];
#pragma unroll
    for (int i = 0; i < 4; i++)
#pragma unroll
      for (int r = 0; r < 4; r++) {
        const int row = row0 + wr * 64 + i * 16 + quad * 4 + r;
        _Float16* cp = C + (size_t)row * N + col0 + wc * 64 + l15;
#pragma unroll
        for (int j = 0; j < 4; j++)
          cp[j * 16] = (_Float16)gelu_f(acc[i][j][r] + bv4[j]);
      }
  } else {
    _Float16* qkout = (_Float16*)Cout;
    const int bx = blockIdx.x;
    if (bx < 2) {
      // q (scaled) or k -> qk[M][256]
      const float* bp = (bx == 0) ? b0p : b1p;
      const float sc = (bx == 0) ? ATT_SCALE : 1.0f;
      const int cofs = bx * 128 + wc * 64 + l15;
      float bv4[4];
#pragma unroll
      for (int j = 0; j < 4; j++) bv4[j] = bp[wc * 64 + j * 16 + l15];
#pragma unroll
      for (int i = 0; i < 4; i++)
#pragma unroll
        for (int r = 0; r < 4; r++) {
          const int row = row0 + wr * 64 + i * 16 + quad * 4 + r;
          _Float16* cp = qkout + (size_t)row * 256 + cofs;
#pragma unroll
          for (int j = 0; j < 4; j++)
            cp[j * 16] = (_Float16)((acc[i][j][r] + bv4[j]) * sc);
        }
    } else {
      // v -> vt[B][128][S], via LDS transpose (Ts[vd][40] f16, aliases SMEM)
      _Float16* Ts = SMEM;
      float bv4[4];
#pragma unroll
      for (int j = 0; j < 4; j++) bv4[j] = b2p[wc * 64 + j * 16 + l15];
      const int bb = row0 >> 11, s0 = row0 & 2047;
#pragma unroll
      for (int c = 0; c < 4; c++) {        // s-chunk [c*32, c*32+32)
        __syncthreads();
        if (wr == (c >> 1)) {
#pragma unroll
          for (int ii = 0; ii < 2; ii++) {
            const int i = (c & 1) * 2 + ii;
#pragma unroll
            for (int j = 0; j < 4; j++) {
              const int vd = wc * 64 + j * 16 + l15;
              const int slocal = ii * 16 + quad * 4;
              ushort4 h;
              h.x = f16bits(acc[i][j][0] + bv4[j]);
              h.y = f16bits(acc[i][j][1] + bv4[j]);
              h.z = f16bits(acc[i][j][2] + bv4[j]);
              h.w = f16bits(acc[i][j][3] + bv4[j]);
              *(ushort4*)&Ts[vd * 40 + slocal] = h;
            }
          }
        }
        __syncthreads();
#pragma unroll
        for (int p = 0; p < 2; p++) {
          const int idx = tid + p * 256;       // 0..511
          const int vd = idx >> 2, s8 = (idx & 3) * 8;
          uint4 d = *(const uint4*)&Ts[vd * 40 + s8];
          *(uint4*)&vtout[((size_t)bb * 128 + vd) * SEQ + s0 + c * 32 + s8] = d;
        }
      }
    }
  }
}

// ---------------- MFMA flash attention ----------------
// Grid (SEQ/64, B), 256 thr = 4 waves, 16 queries/wave. 64-key tiles.
// qk: [B*S][256] f16 (q pre-scaled, k). vt: [B][128][S] f16. H: [B*S][128] f16.
__global__ __launch_bounds__(256) void flash_attn_mfma(const _Float16* __restrict__ qk,
                                                       const _Float16* __restrict__ vt,
                                                       _Float16* __restrict__ H) {
  __shared__ _Float16 Ks[2][64][136];   // keys x d, pad 8
  __shared__ _Float16 Vs[128][72];      // d x keys, pad 8
  __shared__ _Float16 Ps[4][16][72];    // per-wave P: q x keys, pad 8
  const int b = blockIdx.y, q0 = blockIdx.x * 64;
  const int tid = threadIdx.x;
  const int lane = tid & 63, w = tid >> 6;
  const int l15 = lane & 15, quad = lane >> 4;

  // Q fragments (A-layout), q pre-scaled by 1/sqrt(dk)
  f16x8 qf[4];
  {
    const _Float16* qrow = qk + ((size_t)(b * SEQ + q0 + w * 16 + l15)) * 256 + quad * 8;
#pragma unroll
    for (int ks = 0; ks < 4; ks++) qf[ks] = *(const f16x8*)(qrow + ks * 32);
  }
  const f32x4 zero = {0.f, 0.f, 0.f, 0.f};
  f32x4 O[8];
#pragma unroll
  for (int i = 0; i < 8; i++) O[i] = zero;
  float m_r[4] = {-1e30f, -1e30f, -1e30f, -1e30f};
  float l_r[4] = {0.f, 0.f, 0.f, 0.f};

  const _Float16* kg0 = qk + (size_t)(b * SEQ) * 256 + 128 + (size_t)(tid >> 4) * 256 + (tid & 15) * 8;
  const _Float16* vg0 = vt + (size_t)b * 128 * SEQ + (size_t)((tid >> 3)) * SEQ + (tid & 7) * 8;
  uint4 kp[4], vp[4];

#define LOAD_TILE(kt)                                                            \
  {                                                                              \
    const _Float16* kg = kg0 + (size_t)(kt) * 64 * 256;                          \
    const _Float16* vg = vg0 + (size_t)(kt) * 64;                                \
    _Pragma("unroll") for (int p = 0; p < 4; p++) {                              \
      kp[p] = *(const uint4*)(kg + (size_t)p * 16 * 256);                        \
      vp[p] = *(const uint4*)(vg + (size_t)p * 32 * SEQ);                        \
    }                                                                            \
  }
#define STORE_K(buf)                                                             \
  _Pragma("unroll") for (int p = 0; p < 4; p++)                                  \
      *(uint4*)&Ks[buf][(tid >> 4) + 16 * p][(tid & 15) * 8] = kp[p];
#define STORE_V()                                                                \
  _Pragma("unroll") for (int p = 0; p < 4; p++)                                  \
      *(uint4*)&Vs[(tid >> 3) + 32 * p][(tid & 7) * 8] = vp[p];

  LOAD_TILE(0);
  STORE_K(0);
  STORE_V();
  __syncthreads();

  const int NT = SEQ / 64;
  for (int kt = 0; kt < NT; kt++) {
    const int cur = kt & 1;
    if (kt + 1 < NT) LOAD_TILE(kt + 1);

    // S = Q K^T  (4 key-tiles of 16)
    f32x4 s4[4];
#pragma unroll
    for (int nt = 0; nt < 4; nt++) {
      s4[nt] = zero;
#pragma unroll
      for (int ks = 0; ks < 4; ks++) {
        f16x8 kf = *(const f16x8*)&Ks[cur][nt * 16 + l15][ks * 32 + quad * 8];
        s4[nt] = __builtin_amdgcn_mfma_f32_16x16x32_f16(qf[ks], kf, s4[nt], 0, 0, 0);
      }
    }
    // online softmax; row = quad*4 + r, spread over 16 l15 lanes
    float rmax[4], alpha[4], rsum[4];
#pragma unroll
    for (int r = 0; r < 4; r++)
      rmax[r] = fmaxf(fmaxf(s4[0][r], s4[1][r]), fmaxf(s4[2][r], s4[3][r]));
#pragma unroll
    for (int o = 1; o < 16; o <<= 1)
#pragma unroll
      for (int r = 0; r < 4; r++) rmax[r] = fmaxf(rmax[r], __shfl_xor(rmax[r], o, 64));
#pragma unroll
    for (int r = 0; r < 4; r++) {
      const float nm = fmaxf(m_r[r], rmax[r]);
      alpha[r] = __expf(m_r[r] - nm);
      m_r[r] = nm;
#pragma unroll
      for (int nt = 0; nt < 4; nt++) s4[nt][r] = __expf(s4[nt][r] - nm);
      rsum[r] = s4[0][r] + s4[1][r] + s4[2][r] + s4[3][r];
    }
#pragma unroll
    for (int o = 1; o < 16; o <<= 1)
#pragma unroll
      for (int r = 0; r < 4; r++) rsum[r] += __shfl_xor(rsum[r], o, 64);
#pragma unroll
    for (int r = 0; r < 4; r++) {
      l_r[r] = l_r[r] * alpha[r] + rsum[r];
#pragma unroll
      for (int i = 0; i < 8; i++) O[i][r] *= alpha[r];
    }
    // P -> LDS (C-layout write), read back in A-layout (same wave, in-order DS)
#pragma unroll
    for (int nt = 0; nt < 4; nt++)
#pragma unroll
      for (int r = 0; r < 4; r++)
        Ps[w][quad * 4 + r][nt * 16 + l15] = (_Float16)s4[nt][r];
    f16x8 pa[2];
#pragma unroll
    for (int ks = 0; ks < 2; ks++)
      pa[ks] = *(const f16x8*)&Ps[w][l15][ks * 32 + quad * 8];
    // O += P @ V  (8 vdim-tiles of 16)
#pragma unroll
    for (int ks = 0; ks < 2; ks++)
#pragma unroll
      for (int vt8 = 0; vt8 < 8; vt8++) {
        f16x8 vf = *(const f16x8*)&Vs[vt8 * 16 + l15][ks * 32 + quad * 8];
        O[vt8] = __builtin_amdgcn_mfma_f32_16x16x32_f16(pa[ks], vf, O[vt8], 0, 0, 0);
      }

    if (kt + 1 < NT) {
      STORE_K(cur ^ 1);        // other K buffer: safe without barrier
      __syncthreads();         // all waves done reading Vs for this tile
      STORE_V();
      __syncthreads();         // next tile K+V visible
    }
  }
  // epilogue: H[q][vd] = O / l
#pragma unroll
  for (int r = 0; r < 4; r++) {
    const float inv = 1.0f / l_r[r];
    _Float16* hp = H + (size_t)(b * SEQ + q0 + w * 16 + quad * 4 + r) * D_HEAD;
#pragma unroll
    for (int vt8 = 0; vt8 < 8; vt8++)
      hp[vt8 * 16 + l15] = (_Float16)(O[vt8][r] * inv);
  }
}

// ---------------- launch ----------------
extern "C" void kernel_launch(void* const* d_in, const int* in_sizes, int n_in,
                              void* d_out, int out_size, void* d_ws, size_t ws_size,
                              hipStream_t stream) {
  const float* x     = (const float*)d_in[0];
  const float* ln1_g = (const float*)d_in[1];
  const float* ln1_b = (const float*)d_in[2];
  const float* Wq    = (const float*)d_in[3];
  const float* bq    = (const float*)d_in[4];
  const float* Wk    = (const float*)d_in[5];
  const float* bk    = (const float*)d_in[6];
  const float* Wv    = (const float*)d_in[7];
  const float* bv    = (const float*)d_in[8];
  const float* Wo    = (const float*)d_in[9];
  const float* bo    = (const float*)d_in[10];
  const float* ln2_g = (const float*)d_in[11];
  const float* ln2_b = (const float*)d_in[12];
  const float* W1    = (const float*)d_in[13];
  const float* b1    = (const float*)d_in[14];
  const float* W2    = (const float*)d_in[15];
  const float* b2    = (const float*)d_in[16];
  float* out = (float*)d_out;

  // Workspace (<=180 MiB), lifetime-overlapped:
  //  [0,8M) W1T | [8,16M) W2T | [16,16.75M) WqkvT | [16.75,17M) WoT
  //  [20,84M) xn_f32 (K1..K4) | [84,116M) xn_f16 (K1..K2)
  //  [116,124M) qk (K2..K3) | [124,128M) vt (K2..K3) | [128,132M) Hb (K3..K4)
  //  [20,148M) act f16 (K6..K7, reuses dead buffers) | [148,180M) h16 (K5..K6)
  char* ws = (char*)d_ws;
  const size_t MB = 1024 * 1024;
  _Float16* W1T   = (_Float16*)(ws);
  _Float16* W2T   = (_Float16*)(ws + 8 * MB);
  _Float16* WqkvT = (_Float16*)(ws + 16 * MB);
  _Float16* WoT   = (_Float16*)(ws + 16 * MB + 768 * 1024);
  float*    xn_f32 = (float*)(ws + 20 * MB);
  _Float16* xn_f16 = (_Float16*)(ws + 84 * MB);
  _Float16* qkb  = (_Float16*)(ws + 116 * MB);
  _Float16* vtb  = (_Float16*)(ws + 124 * MB);
  _Float16* Hb   = (_Float16*)(ws + 128 * MB);
  _Float16* act  = (_Float16*)(ws + 20 * MB);
  _Float16* h16  = (_Float16*)(ws + 148 * MB);

  // K0: weight convert+transpose (Wq/Wk/Wv into one contiguous [384][1024])
  convt_kernel<<<dim3(D_FF / 32, D_MODEL / 32), 256, 0, stream>>>(W1, W1T, D_MODEL, D_FF);
  convt_kernel<<<dim3(D_MODEL / 32, D_FF / 32), 256, 0, stream>>>(W2, W2T, D_FF, D_MODEL);
  convt_kernel<<<dim3(D_HEAD / 32, D_MODEL / 32), 256, 0, stream>>>(Wq, WqkvT, D_MODEL, D_HEAD);
  convt_kernel<<<dim3(D_HEAD / 32, D_MODEL / 32), 256, 0, stream>>>(Wk, WqkvT + 128 * 1024, D_MODEL, D_HEAD);
  convt_kernel<<<dim3(D_HEAD / 32, D_MODEL / 32), 256, 0, stream>>>(Wv, WqkvT + 256 * 1024, D_MODEL, D_HEAD);
  convt_kernel<<<dim3(D_MODEL / 32, D_HEAD / 32), 256, 0, stream>>>(Wo, WoT, D_HEAD, D_MODEL);
  // K1: LN1
  ln_kernel<true><<<dim3(M_TOT), 256, 0, stream>>>(x, ln1_g, ln1_b, xn_f32, xn_f16);
  // K2: fused QKV projection -> qk[M][256] (q scaled) + vt[B][128][S]
  mfma_gemm<2><<<dim3(3, M_TOT / 128), 256, 0, stream>>>(
      xn_f16, WqkvT, bq, bk, bv, nullptr, qkb, vtb, M_TOT, 384, D_MODEL);
  // K3: flash attention -> Hb f16
  flash_attn_mfma<<<dim3(SEQ / 64, NBATCH), 256, 0, stream>>>(qkb, vtb, Hb);
  // K4: y = xn + H @ Wo + bo -> out f32  (pipelined 256^2 GEMM, NKT=4)
  mfma_gemm256<0><<<dim3((D_MODEL / 256) * (M_TOT / 256)), 512, 0, stream>>>(
      Hb, WoT, bo, xn_f32, out, M_TOT, D_MODEL, D_HEAD);
  // K5: LN2 -> h16
  ln_kernel<false><<<dim3(M_TOT), 256, 0, stream>>>(out, ln2_g, ln2_b, nullptr, h16);
  // K6: act = gelu(h @ W1 + b1) f16
  mfma_gemm256<1><<<dim3((D_FF / 256) * (M_TOT / 256)), 512, 0, stream>>>(
      h16, W1T, b1, nullptr, act, M_TOT, D_FF, D_MODEL);
  // K7: out = y + act @ W2 + b2
  mfma_gemm256<0><<<dim3((D_MODEL / 256) * (M_TOT / 256)), 512, 0, stream>>>(
      act, W2T, b2, out, out, M_TOT, D_MODEL, D_FF);

  (void)in_sizes; (void)n_in; (void)out_size; (void)ws_size;
}